// Round 9
// baseline (168.335 us; speedup 1.0000x reference)
//
#include <hip/hip_runtime.h>
#include <hip/hip_bf16.h>

#define S_LEN 4096
#define HID   512
#define HD    128
#define LOG2_GAMMA (-0.0458036933f)   // log2(0.96875)

typedef short bf16x8 __attribute__((ext_vector_type(8)));
typedef float f32x4  __attribute__((ext_vector_type(4)));
typedef unsigned short u16;

static __device__ __forceinline__ u16 f2bf(float f) {
    union { float f; unsigned u; } v; v.f = f;
    unsigned r = (v.u + 0x7fffu + ((v.u >> 16) & 1u)) >> 16;  // RNE
    return (u16)r;
}

static __device__ __forceinline__ unsigned pk2(float lo, float hi) {
    __hip_bfloat162 h = __float22bfloat162_rn(make_float2(lo, hi));
    union { __hip_bfloat162 h; unsigned u; } c; c.h = h; return c.u;
}
static __device__ __forceinline__ bf16x8 pack8(float4 a, float4 b) {
    union { unsigned u[4]; bf16x8 v; } r;
    r.u[0] = pk2(a.x, a.y); r.u[1] = pk2(a.z, a.w);
    r.u[2] = pk2(b.x, b.y); r.u[3] = pk2(b.z, b.w);
    return r.v;
}

// async global->LDS, 16B per lane; LDS dest = wave-uniform base + lane*16
static __device__ __forceinline__ void gload16(const void* g, void* l) {
    __builtin_amdgcn_global_load_lds(
        (const __attribute__((address_space(1))) unsigned*)g,
        (__attribute__((address_space(3))) unsigned*)l, 16, 0, 0);
}

// ---------------- prep: xpos tables (blocks 0..1023) + weight transpose (1024..1791)
__global__ __launch_bounds__(256) void prep_kernel(const float* __restrict__ WQ,
                                                   const float* __restrict__ WK,
                                                   const float* __restrict__ WV,
                                                   u16* __restrict__ Wt,
                                                   float2* __restrict__ tabQ,
                                                   float2* __restrict__ tabK) {
    if (blockIdx.x < 1024) {
        int idx = blockIdx.x * 256 + threadIdx.x;      // 4096*64 items
        int n = idx >> 6, i = idx & 63;
        float base  = (2.0f * i + 51.2f) * (1.0f / 179.2f);   // (2i+0.4d)/(1.4d), d=128
        float power = (float)n * (1.0f / 512.0f);
        float scale = exp2f(power * log2f(base));
        float inv_freq = exp2f(-(float)i * (13.287712379549449f / 64.0f)); // 10000^(-i/64)
        float theta = (float)n * inv_freq;
        float s, c;
        sincosf(theta, &s, &c);
        tabQ[idx] = make_float2(c * scale, s * scale);
        float is = 1.0f / scale;
        tabK[idx] = make_float2(c * is, s * is);
    } else {
        int idx = (blockIdx.x - 1024) * 256 + threadIdx.x;   // 3*128*512 items
        int w = idx >> 16;
        int rem = idx & 65535;
        int c = rem >> 9, k = rem & 511;
        const float* src = (w == 0) ? WQ : (w == 1) ? WK : WV;
        Wt[idx] = f2bf(src[k * HD + c]);
    }
}

// ---------------- proj v8: ONE-WAVE blocks, zero barriers, wave-private dbuf -------
// grid (256, 8); block 64 (1 wave). y<4: Q col-group y; y>=4: K+V col-group y-4.
// Block computes 64 rows x 32 cols over K=512 in 16 chunks of BK=32.
// A (64x32 fp32) and B (32x32 bf16 per mat) staged into wave-private LDS via
// global_load_lds; chunk loop unrolled x2 so buffer index is compile-time ->
// compiler can prove buf disjointness and emit fine-grained vmcnt (no barrier!).
// Swizzles (bank-balance for ds_read_b128): A unit s of row r at r*8+(s^(r&7));
// B unit s of col c at c*4+(s^((c>>1)&3)).
__global__ __launch_bounds__(64) void proj_kernel(const float* __restrict__ X,
                                                  const float* __restrict__ Mem,
                                                  const u16* __restrict__ Wt,
                                                  const float2* __restrict__ tabQ,
                                                  const float2* __restrict__ tabK,
                                                  u16* __restrict__ Qo,
                                                  u16* __restrict__ Ko,
                                                  u16* __restrict__ Vt) {
    __shared__ __align__(16) float A_lds[2][2048];     // 2 x 8KB: 64 rows x 32 k
    __shared__ __align__(16) u16   B_lds[2][2][1024];  // 2 bufs x 2 mats x 2KB
    const int lane = threadIdx.x;
    const int l15  = lane & 15, quad = lane >> 4;
    const int rt_base = blockIdx.x * 64;
    const bool isQ = (blockIdx.y < 4);
    const int cg = blockIdx.y & 3;                     // col-group: cols cg*32..+32
    const float* src = isQ ? X : Mem;
    const u16* W0 = isQ ? Wt : (Wt + 65536);           // Q or K weights
    const u16* W1 = Wt + 131072;                       // V (KV blocks only)

    auto stageA = [&](int ch, int p) {
        const int kc0 = ch * 32;
#pragma unroll
        for (int i = 0; i < 8; ++i) {
            int L = i * 64 + lane;
            int row = L >> 3;
            int s = (L & 7) ^ (row & 7);
            gload16(src + (size_t)(rt_base + row) * HID + kc0 + s * 4,
                    &A_lds[p][i * 256]);
        }
    };
    auto stageB = [&](const u16* W, int m, int ch, int p) {
        const int kc0 = ch * 32;
#pragma unroll
        for (int i = 0; i < 2; ++i) {
            int L = i * 64 + lane;
            int col = L >> 2;
            int s = (L & 3) ^ ((col >> 1) & 3);
            gload16(W + (size_t)(cg * 32 + col) * HID + kc0 + s * 8,
                    &B_lds[p][m][i * 512]);
        }
    };

    f32x4 acc0[4][2], acc1[4][2];
#pragma unroll
    for (int rt = 0; rt < 4; ++rt)
#pragma unroll
        for (int ct = 0; ct < 2; ++ct) {
            acc0[rt][ct] = (f32x4){0.f, 0.f, 0.f, 0.f};
            acc1[rt][ct] = (f32x4){0.f, 0.f, 0.f, 0.f};
        }

    auto compute = [&](int p) {
#pragma unroll
        for (int rt = 0; rt < 4; ++rt) {
            const int ar = rt * 16 + l15;
            float4 af0 = *(const float4*)&A_lds[p][(ar * 8 + ((quad * 2    ) ^ (ar & 7))) * 4];
            float4 af1 = *(const float4*)&A_lds[p][(ar * 8 + ((quad * 2 + 1) ^ (ar & 7))) * 4];
            bf16x8 a = pack8(af0, af1);
#pragma unroll
            for (int ct = 0; ct < 2; ++ct) {
                const int bu = (ct * 16 + l15) * 4 + (quad ^ ((l15 >> 1) & 3));
                bf16x8 b0 = *(const bf16x8*)&B_lds[p][0][bu * 8];
                acc0[rt][ct] = __builtin_amdgcn_mfma_f32_16x16x32_bf16(a, b0, acc0[rt][ct], 0, 0, 0);
                if (!isQ) {
                    bf16x8 b1 = *(const bf16x8*)&B_lds[p][1][bu * 8];
                    acc1[rt][ct] = __builtin_amdgcn_mfma_f32_16x16x32_bf16(a, b1, acc1[rt][ct], 0, 0, 0);
                }
            }
        }
    };

    // prime buf0, then [stage next | compute cur], unrolled x2 (p compile-time)
    stageA(0, 0); stageB(W0, 0, 0, 0); if (!isQ) stageB(W1, 1, 0, 0);
    for (int ch = 0; ch < 16; ch += 2) {
        if (ch + 1 < 16) { stageA(ch + 1, 1); stageB(W0, 0, ch + 1, 1); if (!isQ) stageB(W1, 1, ch + 1, 1); }
        compute(0);
        if (ch + 2 < 16) { stageA(ch + 2, 0); stageB(W0, 0, ch + 2, 0); if (!isQ) stageB(W1, 1, ch + 2, 0); }
        if (ch + 1 < 16) compute(1);
    }

    // ---- xpos epilogue for Q / K (table) ----
    {
        const float2* tab = isQ ? tabQ : tabK;
        u16* outp = isQ ? Qo : Ko;
#pragma unroll
        for (int ct = 0; ct < 2; ++ct) {
            int j = cg * 32 + ct * 16 + l15;
            int i = j >> 1;
            float sgn = (j & 1) ? 1.0f : -1.0f;   // rot[2i]=-x[2i+1], rot[2i+1]=+x[2i]
#pragma unroll
            for (int rt = 0; rt < 4; ++rt) {
#pragma unroll
                for (int r = 0; r < 4; ++r) {
                    int t = rt_base + rt * 16 + quad * 4 + r;
                    int n = t & 4095;
                    float2 cs = tab[n * 64 + i];
                    float v = acc0[rt][ct][r];
                    float partner = __shfl_xor(v, 1, 64);
                    outp[(size_t)t * HD + j] = f2bf(v * cs.x + sgn * partner * cs.y);
                }
            }
        }
    }

    if (!isQ) {
        // V transpose via wave-private LDS scratch (reuses A_lds[0]) -> Vt[b][h][s]
        u16* Vs = (u16*)&A_lds[0][0];                  // 32 x 72 u16 = 4.6KB
#pragma unroll
        for (int ct = 0; ct < 2; ++ct) {
            int cl = ct * 16 + l15;
#pragma unroll
            for (int rt = 0; rt < 4; ++rt)
#pragma unroll
                for (int r = 0; r < 4; ++r)
                    Vs[cl * 72 + rt * 16 + quad * 4 + r] = f2bf(acc1[rt][ct][r]);
        }
        // same wave wrote: lgkmcnt ordering only, no barrier
        int b = rt_base >> 12, sb = rt_base & 4095;
        int hl = lane >> 1, sof = (lane & 1) * 32;
        int h = cg * 32 + hl;
#pragma unroll
        for (int pp = 0; pp < 4; ++pp) {
            bf16x8 v = *(const bf16x8*)&Vs[hl * 72 + sof + pp * 8];
            *(bf16x8*)(Vt + (size_t)(b * 128 + h) * S_LEN + sb + sof + pp * 8) = v;
        }
    }
}

// ---------------- retention v6: ONE-WAVE blocks, zero barriers ---------------------
// grid 1024 (b*256 + qtile16); block 64 (1 wave owns 16 q-rows, all 128 head-cols).
// K tiles (64 kv x 128 hd) wave-private double-buffered via global_load_lds;
// V direct to registers; P strip wave-private LDS. No __syncthreads anywhere.
__global__ __launch_bounds__(64) void ret_kernel(const u16* __restrict__ Qb,
                                                 const u16* __restrict__ Kb,
                                                 const u16* __restrict__ Vt,
                                                 float* __restrict__ out) {
    __shared__ __align__(16) u16   K_lds[2][8192];     // 2 x 16KB: 64 kv x 128 hd
    __shared__ __align__(16) float P_lds[16][68];      // wave-private 16x64 fp32
    const int lane = threadIdx.x;
    const int l15  = lane & 15, quad = lane >> 4;
    const int b  = blockIdx.x >> 8;
    const int qw = (blockIdx.x & 255) * 16;

    auto stageK = [&](int kv0, int p) {
#pragma unroll
        for (int i = 0; i < 16; ++i) {
            int L = i * 64 + lane;
            int kvr = L >> 4;
            int s = (L & 15) ^ (kvr & 15);
            gload16(Kb + (size_t)(b * S_LEN + kv0 + kvr) * HD + s * 8,
                    &K_lds[p][i * 512]);
        }
    };

    const size_t tq = (size_t)(b * S_LEN + qw + l15);
    bf16x8 qfrag[4];
#pragma unroll
    for (int kc = 0; kc < 4; ++kc)
        qfrag[kc] = *(const bf16x8*)(Qb + tq * HD + kc * 32 + quad * 8);

    f32x4 acco[8];
#pragma unroll
    for (int ht = 0; ht < 8; ++ht) acco[ht] = (f32x4){0.f, 0.f, 0.f, 0.f};

    int kv_lo = (qw - 448) & ~63;                      // d<=448 covered; 64-aligned
    if (kv_lo < 0) kv_lo = 0;
    const int nt = (qw + 16 - kv_lo + 63) >> 6;        // <= 8 tiles

    auto tile = [&](int it, int p) {
        const int kv0 = kv_lo + it * 64;
        // V prefetch (global->reg) issued first, consumed after QK
        bf16x8 vf[8][2];
#pragma unroll
        for (int ht = 0; ht < 8; ++ht) {
            const u16* vb = Vt + (size_t)(b * HD + ht * 16 + l15) * S_LEN + kv0 + quad * 8;
            vf[ht][0] = *(const bf16x8*)vb;
            vf[ht][1] = *(const bf16x8*)(vb + 32);
        }
        // S = Q K^T (16x64)
        f32x4 accs[4];
#pragma unroll
        for (int ct = 0; ct < 4; ++ct) accs[ct] = (f32x4){0.f, 0.f, 0.f, 0.f};
#pragma unroll
        for (int ct = 0; ct < 4; ++ct) {
            const int kvr = ct * 16 + l15;
#pragma unroll
            for (int kc = 0; kc < 4; ++kc) {
                bf16x8 kf = *(const bf16x8*)
                    &K_lds[p][(kvr * 16 + ((kc * 4 + quad) ^ (kvr & 15))) * 8];
                accs[ct] = __builtin_amdgcn_mfma_f32_16x16x32_bf16(qfrag[kc], kf, accs[ct], 0, 0, 0);
            }
        }
        // decay + causal mask -> P (wave-private)
#pragma unroll
        for (int ct = 0; ct < 4; ++ct) {
            int kvi = kv0 + ct * 16 + l15;
#pragma unroll
            for (int r = 0; r < 4; ++r) {
                int d = (qw + quad * 4 + r) - kvi;
                float w = exp2f((float)d * LOG2_GAMMA);
                P_lds[quad * 4 + r][ct * 16 + l15] = (d >= 0) ? accs[ct][r] * w : 0.0f;
            }
        }
        float4 p00 = *(const float4*)&P_lds[l15][quad * 8];
        float4 p01 = *(const float4*)&P_lds[l15][quad * 8 + 4];
        float4 p10 = *(const float4*)&P_lds[l15][32 + quad * 8];
        float4 p11 = *(const float4*)&P_lds[l15][32 + quad * 8 + 4];
        bf16x8 pa0 = pack8(p00, p01);
        bf16x8 pa1 = pack8(p10, p11);
#pragma unroll
        for (int ht = 0; ht < 8; ++ht) {
            acco[ht] = __builtin_amdgcn_mfma_f32_16x16x32_bf16(pa0, vf[ht][0], acco[ht], 0, 0, 0);
            acco[ht] = __builtin_amdgcn_mfma_f32_16x16x32_bf16(pa1, vf[ht][1], acco[ht], 0, 0, 0);
        }
    };

    // dbuf pipeline, unrolled x2 for compile-time buffer index
    stageK(kv_lo, 0);
    for (int it = 0; it < nt; it += 2) {
        if (it + 1 < nt) stageK(kv_lo + (it + 1) * 64, 1);
        tile(it, 0);
        if (it + 2 < nt) stageK(kv_lo + (it + 2) * 64, 0);
        if (it + 1 < nt) tile(it + 1, 1);
    }

#pragma unroll
    for (int ht = 0; ht < 8; ++ht)
#pragma unroll
        for (int r = 0; r < 4; ++r)
            out[(size_t)(b * S_LEN + qw + quad * 4 + r) * HD + ht * 16 + l15] = acco[ht][r];
}

extern "C" void kernel_launch(void* const* d_in, const int* in_sizes, int n_in,
                              void* d_out, int out_size, void* d_ws, size_t ws_size,
                              hipStream_t stream) {
    const float* X   = (const float*)d_in[0];
    const float* Mem = (const float*)d_in[1];
    const float* WQ  = (const float*)d_in[2];
    const float* WK  = (const float*)d_in[3];
    const float* WV  = (const float*)d_in[4];
    float* out = (float*)d_out;

    char* ws = (char*)d_ws;
    u16*    Qb   = (u16*)(ws);                         // 4 MB  bf16 [16384][128]
    u16*    Kb   = (u16*)(ws + ((size_t)4 << 20));     // 4 MB
    u16*    Vt   = (u16*)(ws + ((size_t)8 << 20));     // 4 MB  bf16 [4][128][4096]
    u16*    Wt   = (u16*)(ws + ((size_t)12 << 20));    // 384 KB bf16 [3][128][512]
    float2* tabQ = (float2*)(ws + ((size_t)13 << 20)); // 2 MB
    float2* tabK = (float2*)(ws + ((size_t)15 << 20)); // 2 MB

    prep_kernel<<<dim3(1792), dim3(256), 0, stream>>>(WQ, WK, WV, Wt, tabQ, tabK);
    proj_kernel<<<dim3(256, 8), dim3(64), 0, stream>>>(X, Mem, Wt, tabQ, tabK, Qb, Kb, Vt);
    ret_kernel<<<dim3(1024), dim3(64), 0, stream>>>(Qb, Kb, Vt, out);
}